// Round 7
// baseline (260.696 us; speedup 1.0000x reference)
//
#include <hip/hip_runtime.h>
#include <cstdint>
#include <cstddef>

// Problem constants (from reference)
constexpr int N  = 2048;     // parents
constexpr int C  = 256;      // in channels
constexpr int CO = 128;      // out channels
constexpr int M  = 16384;    // children (8*N)
constexpr int G  = 66;       // padded child grid dim (S2+2)
constexpr int KP = 7;        // k-split parts
constexpr int KCHUNK = 4;    // neighbors per part (4,4,4,4,4,4,3)
constexpr float EPS = 1e-6f;

using bf8 = __attribute__((ext_vector_type(8))) short;   // 8 bf16 (4 VGPRs)
using f4  = __attribute__((ext_vector_type(4))) float;   // 4 f32 acc

static __device__ __forceinline__ unsigned short f2bf(float f) {
  unsigned u = __float_as_uint(f);
  u += 0x7fffu + ((u >> 16) & 1u);     // round-to-nearest-even
  return (unsigned short)(u >> 16);
}
static __device__ __forceinline__ float bf2f(unsigned short s) {
  return __uint_as_float((unsigned)s << 16);
}

// ------ prep: tiled weight transposes (coalesced both sides) + grid init -----
__global__ __launch_bounds__(256) void k_prep(
    const float* __restrict__ c1w, unsigned short* __restrict__ w1t,
    const float* __restrict__ c2w, unsigned short* __restrict__ w2t,
    int* __restrict__ grid, unsigned short* __restrict__ h,
    unsigned short* __restrict__ h1) {
  int i = blockIdx.x * 256 + threadIdx.x;
  if (i < G * G * G) grid[i] = M;
  if (blockIdx.x == 1200) {
    if (threadIdx.x < C) h[(size_t)N * C + threadIdx.x] = 0;
  }
  if (blockIdx.x == 1201) {
    if (threadIdx.x < CO) h1[(size_t)M * CO + threadIdx.x] = 0;
  }

  __shared__ float tile[32][33];
  int bx = blockIdx.x;
  const float* w; unsigned short* wtp; int cin, k, cb, ob;
  if (bx < 864) {                      // conv1: CIN=256 -> 8 cb x 4 ob per k
    w = c1w; wtp = w1t; cin = C;
    k = bx >> 5; int tl = bx & 31; cb = tl >> 2; ob = tl & 3;
  } else {                             // conv2: CIN=128 -> 4 cb x 4 ob per k
    int b2 = bx - 864;
    w = c2w; wtp = w2t; cin = CO;
    k = b2 >> 4; int tl = b2 & 15; cb = tl >> 2; ob = tl & 3;
  }
  int ty = threadIdx.x >> 5, tx = threadIdx.x & 31;
#pragma unroll
  for (int j = 0; j < 4; ++j) {        // read w[k][cb*32+row][ob*32+tx]
    int row = ty + j * 8;
    tile[row][tx] = w[((size_t)k * cin + cb * 32 + row) * CO + ob * 32 + tx];
  }
  __syncthreads();
#pragma unroll
  for (int j = 0; j < 4; ++j) {        // write wt[k][ob*32+row][cb*32+tx]
    int row = ty + j * 8;
    wtp[((size_t)k * CO + ob * 32 + row) * cin + cb * 32 + tx] =
        f2bf(tile[tx][row]);
  }
}

// --- per-parent: subdiv + mask + LN + silu -> h; child scatter; skip GEMM ----
__global__ __launch_bounds__(256) void k_rownorm(
    const float* __restrict__ feats, const float* __restrict__ n1w,
    const float* __restrict__ n1b, const float* __restrict__ sdw,
    const float* __restrict__ sdb, float* __restrict__ out_subdiv,
    unsigned short* __restrict__ h, int* __restrict__ pidx,
    float* __restrict__ maskf, const int* __restrict__ coords,
    int* __restrict__ grid, const float* __restrict__ skw,
    const float* __restrict__ skb, float* __restrict__ sres) {
  int n = blockIdx.x, t = threadIdx.x;
  __shared__ float sx[256];
  __shared__ float sacc[256];
  float x = feats[(size_t)n * C + t];
  sx[t] = x;
  float4 w0 = *(const float4*)(sdw + t * 8);
  float4 w1 = *(const float4*)(sdw + t * 8 + 4);
  float v[10] = {x * w0.x, x * w0.y, x * w0.z, x * w0.w,
                 x * w1.x, x * w1.y, x * w1.z, x * w1.w, x, x * x};
#pragma unroll
  for (int mk = 1; mk < 64; mk <<= 1) {
#pragma unroll
    for (int j = 0; j < 10; ++j) v[j] += __shfl_xor(v[j], mk, 64);
  }
  __shared__ float red[4][10];
  int wave = t >> 6, lane = t & 63;
  if (lane == 0) {
#pragma unroll
    for (int j = 0; j < 10; ++j) red[wave][j] = v[j];
  }
  __syncthreads();
  float sums[10];
#pragma unroll
  for (int j = 0; j < 10; ++j)
    sums[j] = red[0][j] + red[1][j] + red[2][j] + red[3][j];
  float mean = sums[8] / (float)C;
  float var  = sums[9] / (float)C - mean * mean;
  float rstd = rsqrtf(var + EPS);
  if (t < 8) {
    float sd = sums[t] + sdb[t];
    out_subdiv[(size_t)n * 8 + t] = sd;
    bool mk = sd > 0.f;
    pidx[n * 8 + t]  = mk ? n : N;   // h row index (N = zero row)
    maskf[n * 8 + t] = mk ? 1.f : 0.f;
    int xx = coords[n * 3 + 0] * 2 + ((t >> 2) & 1) + 1;
    int yy = coords[n * 3 + 1] * 2 + ((t >> 1) & 1) + 1;
    int zz = coords[n * 3 + 2] * 2 + (t & 1) + 1;
    grid[(xx * G + yy) * G + zz] = n * 8 + t;
  }
  float y  = (x - mean) * rstd * n1w[t] + n1b[t];
  float sl = y / (1.f + __expf(-y));
  h[(size_t)n * C + t] = f2bf(sl);

  // skip GEMM: thread (o = t&127, half = t>>7) sums 128 channels
  int o = t & 127, half = t >> 7;
  const float* wp = skw + (size_t)(half * 128) * CO + o;
  const float* xs = sx + half * 128;
  float a = 0.f;
#pragma unroll 8
  for (int c = 0; c < 128; ++c) a += xs[c] * wp[(size_t)c * CO];
  sacc[t] = a;
  __syncthreads();
  if (t < 128) sres[(size_t)n * CO + t] = sacc[t] + sacc[t + 128] + skb[t];
}

// ---------------- build transposed tables nidxt[k][M], g1t[k][M] -------------
__global__ void k_nidx(const int* __restrict__ coords, const int* __restrict__ grid,
                       const int* __restrict__ pidx, int* __restrict__ nidxt,
                       int* __restrict__ g1t) {
  int idx = blockIdx.x * 256 + threadIdx.x;
  if (idx >= M * 27) return;
  int m = idx & (M - 1);          // M = 2^14
  int k = idx >> 14;
  int p = m >> 3, j = m & 7;
  int dx = k / 9 - 1;
  int dy = (k / 3) % 3 - 1;
  int dz = k % 3 - 1;
  int x = coords[p * 3 + 0] * 2 + ((j >> 2) & 1) + 1 + dx;
  int y = coords[p * 3 + 1] * 2 + ((j >> 1) & 1) + 1 + dy;
  int z = coords[p * 3 + 2] * 2 + (j & 1) + 1 + dz;
  int gv = grid[(x * G + y) * G + z];
  nidxt[idx] = gv;                      // index into h1 (M = zero row)
  g1t[idx] = (gv == M) ? N : pidx[gv];  // index into h  (N = zero row)
}

// ---------------- implicit-GEMM conv: A direct from L2, B through LDS --------
// Block: 128 rows x 128 cols, taps [k0,k0+nk) (KP-way split). grid=(M/128,KP).
// A fragments: per-lane 16B gathers straight from L2 (src is hot). B staged
// reg->LDS double-buffered (8KB/buf, XOR swizzle). Indices prefetched 1 tap
// ahead; A/B frags prefetched 1 stage ahead. 4 blocks/CU for latency hiding.
template <int CIN, int NCB>
__global__ __launch_bounds__(256, 4) void k_conv(
    const unsigned short* __restrict__ src, const int* __restrict__ gt,
    const unsigned short* __restrict__ wt, unsigned short* __restrict__ part) {
  __shared__ unsigned short sB[2][128 * 32];   // 8 KB per buf
  const int t = threadIdx.x;
  const int w = t >> 6, lane = t & 63;
  const int quad = lane >> 4, ln = lane & 15;
  const int m0 = blockIdx.x * 128;
  const int kpart = blockIdx.y;
  const int k0 = kpart * KCHUNK;
  const int nk = min(KCHUNK, 27 - k0);
  const int nstage = nk * NCB;
  const int rh = (w >> 1) * 64, ch = (w & 1) * 64;

  // B staging: thread covers wt row row2 = t>>1, chunks c0, c0+1 (XOR swizzle)
  const int row2 = t >> 1;
  const int c0 = (t & 1) * 2;
  const int x3 = (row2 >> 1) & 3;
  const int wsl0 = row2 * 32 + ((c0) ^ x3) * 8;
  const int wsl1 = row2 * 32 + ((c0 + 1) ^ x3) * 8;
  const int slot = (quad ^ ((ln >> 1) & 3)) * 8;   // de-swizzle for frag reads

  // A gather index base: this lane's 4 row-frags are m0+rh+ti*16+ln
  const int* gbase = gt + (size_t)k0 * M + m0 + rh + ln;

  bf8 rb0, rb1;            // B stage regs
  bf8 ra[4], rn[4];        // A frags: current / next stage
  int ga[4], gn[4];        // gather indices: current / next tap

  auto loadB = [&](int s) {
    const int kk = s / NCB, cb = s - kk * NCB;
    const unsigned short* pb =
        wt + ((size_t)(k0 + kk) * CO + row2) * CIN + cb * 32 + c0 * 8;
    rb0 = *(const bf8*)(pb);
    rb1 = *(const bf8*)(pb + 8);
  };
  auto writeB = [&](int buf) {
    *(bf8*)(sB[buf] + wsl0) = rb0;
    *(bf8*)(sB[buf] + wsl1) = rb1;
  };

  f4 acc[16];
  f4 zero = {0.f, 0.f, 0.f, 0.f};
#pragma unroll
  for (int i = 0; i < 16; ++i) acc[i] = zero;

  // prologue: tap-0 indices, stage-0 A/B
#pragma unroll
  for (int ti = 0; ti < 4; ++ti) ga[ti] = gbase[ti * 16];
  loadB(0);
#pragma unroll
  for (int ti = 0; ti < 4; ++ti)
    ra[ti] = *(const bf8*)(src + (size_t)ga[ti] * CIN + quad * 8);
  writeB(0);

  for (int s = 0; s < nstage; ++s) {
    const int buf = s & 1;
    const int kk = s / NCB, cb = s - kk * NCB;
    const bool have = (s + 1 < nstage);
    // prefetch indices one tap ahead
    if (cb == 0 && kk + 1 < nk) {
#pragma unroll
      for (int ti = 0; ti < 4; ++ti) gn[ti] = gbase[(size_t)(kk + 1) * M + ti * 16];
    }
    // prefetch next stage A/B into regs (overlaps this stage's MFMAs)
    if (have) {
      loadB(s + 1);
      const int cb1 = (cb + 1 < NCB) ? cb + 1 : 0;
      const int* gu = (cb + 1 < NCB) ? ga : gn;
#pragma unroll
      for (int ti = 0; ti < 4; ++ti)
        rn[ti] = *(const bf8*)(src + (size_t)gu[ti] * CIN + cb1 * 32 + quad * 8);
    }
    __syncthreads();                   // stage-s B writes visible
    const unsigned short* pb = sB[buf];
    bf8 bv[4];
#pragma unroll
    for (int tj = 0; tj < 4; ++tj)
      bv[tj] = *(const bf8*)(pb + (ch + tj * 16 + ln) * 32 + slot);
#pragma unroll
    for (int ti = 0; ti < 4; ++ti)
#pragma unroll
      for (int tj = 0; tj < 4; ++tj)
        acc[ti * 4 + tj] = __builtin_amdgcn_mfma_f32_16x16x32_bf16(
            ra[ti], bv[tj], acc[ti * 4 + tj], 0, 0, 0);
    if (have) {
      writeB(buf ^ 1);                 // vmcnt wait lands here, post-MFMA
#pragma unroll
      for (int ti = 0; ti < 4; ++ti) ra[ti] = rn[ti];
      if (cb + 1 == NCB) {
#pragma unroll
        for (int ti = 0; ti < 4; ++ti) ga[ti] = gn[ti];
      }
    }
  }

  // store bf16 partials: D layout col=ln, row=quad*4+rr
  unsigned short* pp = part + ((size_t)kpart * M + m0) * CO;
#pragma unroll
  for (int ti = 0; ti < 4; ++ti) {
    int mrow = rh + ti * 16 + quad * 4;
#pragma unroll
    for (int tj = 0; tj < 4; ++tj) {
      int co = ch + tj * 16 + ln;
#pragma unroll
      for (int rr = 0; rr < 4; ++rr)
        pp[(size_t)(mrow + rr) * CO + co] = f2bf(acc[ti * 4 + tj][rr]);
    }
  }
}

// ---------------- reduce 1: sum KP bf16 partials + bias + LN + silu -> h1 ----
__global__ __launch_bounds__(256) void k_r1(const unsigned short* __restrict__ p,
                                            const float* __restrict__ bias,
                                            unsigned short* __restrict__ h1) {
  int wave = threadIdx.x >> 6, lane = threadIdx.x & 63;
  int m = blockIdx.x * 4 + wave;
  float v0 = bias[lane], v1 = bias[lane + 64];
#pragma unroll
  for (int q = 0; q < KP; ++q) {
    const unsigned short* pq = p + ((size_t)q * M + m) * CO;
    v0 += bf2f(pq[lane]);
    v1 += bf2f(pq[lane + 64]);
  }
  float sum = v0 + v1, sq = v0 * v0 + v1 * v1;
#pragma unroll
  for (int mk = 1; mk < 64; mk <<= 1) {
    sum += __shfl_xor(sum, mk, 64);
    sq  += __shfl_xor(sq, mk, 64);
  }
  float mean = sum / (float)CO;
  float var  = sq / (float)CO - mean * mean;
  float rstd = rsqrtf(var + EPS);
  float y0 = (v0 - mean) * rstd;
  float y1 = (v1 - mean) * rstd;
  float s0 = y0 / (1.f + __expf(-y0));
  float s1 = y1 / (1.f + __expf(-y1));
  h1[(size_t)m * CO + lane]      = f2bf(s0);
  h1[(size_t)m * CO + lane + 64] = f2bf(s1);
}

// ---------------- reduce 2: sum KP bf16 partials + bias + skip, *mask -> out -
__global__ __launch_bounds__(256) void k_r2(const unsigned short* __restrict__ p,
                                            const float* __restrict__ bias,
                                            const float* __restrict__ sres,
                                            const float* __restrict__ maskf,
                                            float* __restrict__ out) {
  int i = blockIdx.x * 256 + threadIdx.x;   // i in [0, M*CO/4)
  int m = i >> 5;                            // 32 groups of 4 per row
  int o4 = (i & 31) * 4;
  float4 acc = *(const float4*)(bias + o4);
#pragma unroll
  for (int q = 0; q < KP; ++q) {
    ushort4 a = *(const ushort4*)(p + ((size_t)q * M + m) * CO + o4);
    acc.x += bf2f(a.x); acc.y += bf2f(a.y);
    acc.z += bf2f(a.z); acc.w += bf2f(a.w);
  }
  float4 s = *(const float4*)(sres + (size_t)(m >> 3) * CO + o4);
  float mk = maskf[m];
  float4 r;
  r.x = (acc.x + s.x) * mk;
  r.y = (acc.y + s.y) * mk;
  r.z = (acc.z + s.z) * mk;
  r.w = (acc.w + s.w) * mk;
  *(float4*)(out + (size_t)m * CO + o4) = r;
}

// ---------------- launcher ----------------------------------------------------
extern "C" void kernel_launch(void* const* d_in, const int* in_sizes, int n_in,
                              void* d_out, int out_size, void* d_ws, size_t ws_size,
                              hipStream_t stream) {
  const float* feats = (const float*)d_in[0];
  const float* n1w   = (const float*)d_in[1];
  const float* n1b   = (const float*)d_in[2];
  const float* sdw   = (const float*)d_in[3];
  const float* sdb   = (const float*)d_in[4];
  const float* c1w   = (const float*)d_in[5];
  const float* c1b   = (const float*)d_in[6];
  const float* c2w   = (const float*)d_in[7];
  const float* c2b   = (const float*)d_in[8];
  const float* skw   = (const float*)d_in[9];
  const float* skb   = (const float*)d_in[10];
  const int* coords  = (const int*)d_in[11];
  float* out = (float*)d_out;   // [M*CO] conv output, then [N*8] subdiv

  char* ws = (char*)d_ws;
  size_t off = 0;
  auto alloc = [&](size_t bytes) -> char* {
    char* p = ws + off;
    off += (bytes + 255) & ~(size_t)255;
    return p;
  };
  unsigned short* h    = (unsigned short*)alloc((size_t)(N + 1) * C * 2);
  unsigned short* h1   = (unsigned short*)alloc((size_t)(M + 1) * CO * 2);
  int*   grid  = (int*)alloc((size_t)G * G * G * 4);
  int*   nidxt = (int*)alloc((size_t)27 * M * 4);
  int*   g1t   = (int*)alloc((size_t)27 * M * 4);
  int*   pidx  = (int*)alloc((size_t)M * 4);
  float* maskf = (float*)alloc((size_t)M * 4);
  float* sres  = (float*)alloc((size_t)N * CO * 4);
  unsigned short* w1t = (unsigned short*)alloc((size_t)27 * CO * C * 2);
  unsigned short* w2t = (unsigned short*)alloc((size_t)27 * CO * CO * 2);
  unsigned short* pc  = (unsigned short*)alloc((size_t)KP * M * CO * 2);

  k_prep<<<1296, 256, 0, stream>>>(c1w, w1t, c2w, w2t, grid, h, h1);
  k_rownorm<<<N, 256, 0, stream>>>(feats, n1w, n1b, sdw, sdb,
                                   out + (size_t)M * CO, h, pidx, maskf,
                                   coords, grid, skw, skb, sres);
  k_nidx<<<(M * 27 + 255) / 256, 256, 0, stream>>>(coords, grid, pidx, nidxt, g1t);

  // conv1: CIN=256 (8 chunks of 32), k-split 6x4+3 -> 896 blocks
  k_conv<C, 8><<<dim3(M / 128, KP), 256, 0, stream>>>(h, g1t, w1t, pc);
  k_r1<<<M / 4, 256, 0, stream>>>(pc, c1b, h1);

  // conv2: CIN=128 (4 chunks of 32)
  k_conv<CO, 4><<<dim3(M / 128, KP), 256, 0, stream>>>(h1, nidxt, w2t, pc);
  k_r2<<<M * CO / 4 / 256, 256, 0, stream>>>(pc, c2b, sres, maskf, out);
}

// Round 8
// 202.772 us; speedup vs baseline: 1.2857x; 1.2857x over previous
//
#include <hip/hip_runtime.h>
#include <cstdint>
#include <cstddef>

// Problem constants (from reference)
constexpr int N  = 2048;     // parents
constexpr int C  = 256;      // in channels
constexpr int CO = 128;      // out channels
constexpr int M  = 16384;    // children (8*N)
constexpr int G  = 66;       // padded child grid dim (S2+2)
constexpr int KP = 7;        // k-split parts
constexpr int KCHUNK = 4;    // neighbors per part (4,4,4,4,4,4,3)
constexpr float EPS = 1e-6f;

using bf8 = __attribute__((ext_vector_type(8))) short;   // 8 bf16 (4 VGPRs)
using f4  = __attribute__((ext_vector_type(4))) float;   // 4 f32 acc

static __device__ __forceinline__ unsigned short f2bf(float f) {
  unsigned u = __float_as_uint(f);
  u += 0x7fffu + ((u >> 16) & 1u);     // round-to-nearest-even
  return (unsigned short)(u >> 16);
}
static __device__ __forceinline__ float bf2f(unsigned short s) {
  return __uint_as_float((unsigned)s << 16);
}

// ------ prep: tiled weight transposes (coalesced both sides) + grid init -----
__global__ __launch_bounds__(256) void k_prep(
    const float* __restrict__ c1w, unsigned short* __restrict__ w1t,
    const float* __restrict__ c2w, unsigned short* __restrict__ w2t,
    int* __restrict__ grid, unsigned short* __restrict__ h,
    unsigned short* __restrict__ h1) {
  int i = blockIdx.x * 256 + threadIdx.x;
  if (i < G * G * G) grid[i] = M;
  if (blockIdx.x == 1200) {
    if (threadIdx.x < C) h[(size_t)N * C + threadIdx.x] = 0;
  }
  if (blockIdx.x == 1201) {
    if (threadIdx.x < CO) h1[(size_t)M * CO + threadIdx.x] = 0;
  }

  __shared__ float tile[32][33];
  int bx = blockIdx.x;
  const float* w; unsigned short* wtp; int cin, k, cb, ob;
  if (bx < 864) {                      // conv1: CIN=256 -> 8 cb x 4 ob per k
    w = c1w; wtp = w1t; cin = C;
    k = bx >> 5; int tl = bx & 31; cb = tl >> 2; ob = tl & 3;
  } else {                             // conv2: CIN=128 -> 4 cb x 4 ob per k
    int b2 = bx - 864;
    w = c2w; wtp = w2t; cin = CO;
    k = b2 >> 4; int tl = b2 & 15; cb = tl >> 2; ob = tl & 3;
  }
  int ty = threadIdx.x >> 5, tx = threadIdx.x & 31;
#pragma unroll
  for (int j = 0; j < 4; ++j) {        // read w[k][cb*32+row][ob*32+tx]
    int row = ty + j * 8;
    tile[row][tx] = w[((size_t)k * cin + cb * 32 + row) * CO + ob * 32 + tx];
  }
  __syncthreads();
#pragma unroll
  for (int j = 0; j < 4; ++j) {        // write wt[k][ob*32+row][cb*32+tx]
    int row = ty + j * 8;
    wtp[((size_t)k * CO + ob * 32 + row) * cin + cb * 32 + tx] =
        f2bf(tile[tx][row]);
  }
}

// --- per-parent: subdiv + mask + LN + silu -> h; child scatter; skip GEMM ----
__global__ __launch_bounds__(256) void k_rownorm(
    const float* __restrict__ feats, const float* __restrict__ n1w,
    const float* __restrict__ n1b, const float* __restrict__ sdw,
    const float* __restrict__ sdb, float* __restrict__ out_subdiv,
    unsigned short* __restrict__ h, int* __restrict__ pidx,
    float* __restrict__ maskf, const int* __restrict__ coords,
    int* __restrict__ grid, const float* __restrict__ skw,
    const float* __restrict__ skb, float* __restrict__ sres) {
  int n = blockIdx.x, t = threadIdx.x;
  __shared__ float sx[256];
  __shared__ float sacc[256];
  float x = feats[(size_t)n * C + t];
  sx[t] = x;
  float4 w0 = *(const float4*)(sdw + t * 8);
  float4 w1 = *(const float4*)(sdw + t * 8 + 4);
  float v[10] = {x * w0.x, x * w0.y, x * w0.z, x * w0.w,
                 x * w1.x, x * w1.y, x * w1.z, x * w1.w, x, x * x};
#pragma unroll
  for (int mk = 1; mk < 64; mk <<= 1) {
#pragma unroll
    for (int j = 0; j < 10; ++j) v[j] += __shfl_xor(v[j], mk, 64);
  }
  __shared__ float red[4][10];
  int wave = t >> 6, lane = t & 63;
  if (lane == 0) {
#pragma unroll
    for (int j = 0; j < 10; ++j) red[wave][j] = v[j];
  }
  __syncthreads();
  float sums[10];
#pragma unroll
  for (int j = 0; j < 10; ++j)
    sums[j] = red[0][j] + red[1][j] + red[2][j] + red[3][j];
  float mean = sums[8] / (float)C;
  float var  = sums[9] / (float)C - mean * mean;
  float rstd = rsqrtf(var + EPS);
  if (t < 8) {
    float sd = sums[t] + sdb[t];
    out_subdiv[(size_t)n * 8 + t] = sd;
    bool mk = sd > 0.f;
    pidx[n * 8 + t]  = mk ? n : N;   // h row index (N = zero row)
    maskf[n * 8 + t] = mk ? 1.f : 0.f;
    int xx = coords[n * 3 + 0] * 2 + ((t >> 2) & 1) + 1;
    int yy = coords[n * 3 + 1] * 2 + ((t >> 1) & 1) + 1;
    int zz = coords[n * 3 + 2] * 2 + (t & 1) + 1;
    grid[(xx * G + yy) * G + zz] = n * 8 + t;
  }
  float y  = (x - mean) * rstd * n1w[t] + n1b[t];
  float sl = y / (1.f + __expf(-y));
  h[(size_t)n * C + t] = f2bf(sl);

  // skip GEMM: thread (o = t&127, half = t>>7) sums 128 channels
  int o = t & 127, half = t >> 7;
  const float* wp = skw + (size_t)(half * 128) * CO + o;
  const float* xs = sx + half * 128;
  float a = 0.f;
#pragma unroll 8
  for (int c = 0; c < 128; ++c) a += xs[c] * wp[(size_t)c * CO];
  sacc[t] = a;
  __syncthreads();
  if (t < 128) sres[(size_t)n * CO + t] = sacc[t] + sacc[t + 128] + skb[t];
}

// ---------------- build transposed tables nidxt[k][M], g1t[k][M] -------------
__global__ void k_nidx(const int* __restrict__ coords, const int* __restrict__ grid,
                       const int* __restrict__ pidx, int* __restrict__ nidxt,
                       int* __restrict__ g1t) {
  int idx = blockIdx.x * 256 + threadIdx.x;
  if (idx >= M * 27) return;
  int m = idx & (M - 1);          // M = 2^14
  int k = idx >> 14;
  int p = m >> 3, j = m & 7;
  int dx = k / 9 - 1;
  int dy = (k / 3) % 3 - 1;
  int dz = k % 3 - 1;
  int x = coords[p * 3 + 0] * 2 + ((j >> 2) & 1) + 1 + dx;
  int y = coords[p * 3 + 1] * 2 + ((j >> 1) & 1) + 1 + dy;
  int z = coords[p * 3 + 2] * 2 + (j & 1) + 1 + dz;
  int gv = grid[(x * G + y) * G + z];
  nidxt[idx] = gv;                      // index into h1 (M = zero row)
  g1t[idx] = (gv == M) ? N : pidx[gv];  // index into h  (N = zero row)
}

// ---------------- implicit-GEMM conv: A direct from L2, B through LDS --------
// Block: 128 rows x 128 cols, taps [k0,k0+nk) (KP-way split). grid=(M/128,KP).
// A fragments: per-lane 16B gathers straight from L2 (src is hot). B staged
// reg->LDS double-buffered (8KB/buf, XOR swizzle). Indices prefetched 1 tap
// ahead; A/B frags prefetched 1 stage ahead.
// __launch_bounds__(256,3): 170 reg/wave cap >= ~136 needed (64 AGPR acc +
// ~72 arch, r6 measured) -> no spill, 3 blocks/CU resident. (256,4) spilled
// to scratch (r7: FETCH +6MB, WRITE +15MB, MfmaUtil halved) - do not re-try.
template <int CIN, int NCB>
__global__ __launch_bounds__(256, 3) void k_conv(
    const unsigned short* __restrict__ src, const int* __restrict__ gt,
    const unsigned short* __restrict__ wt, unsigned short* __restrict__ part) {
  __shared__ unsigned short sB[2][128 * 32];   // 8 KB per buf
  const int t = threadIdx.x;
  const int w = t >> 6, lane = t & 63;
  const int quad = lane >> 4, ln = lane & 15;
  const int m0 = blockIdx.x * 128;
  const int kpart = blockIdx.y;
  const int k0 = kpart * KCHUNK;
  const int nk = min(KCHUNK, 27 - k0);
  const int nstage = nk * NCB;
  const int rh = (w >> 1) * 64, ch = (w & 1) * 64;

  // B staging: thread covers wt row row2 = t>>1, chunks c0, c0+1 (XOR swizzle)
  const int row2 = t >> 1;
  const int c0 = (t & 1) * 2;
  const int x3 = (row2 >> 1) & 3;
  const int wsl0 = row2 * 32 + ((c0) ^ x3) * 8;
  const int wsl1 = row2 * 32 + ((c0 + 1) ^ x3) * 8;
  const int slot = (quad ^ ((ln >> 1) & 3)) * 8;   // de-swizzle for frag reads

  // A gather index base: this lane's 4 row-frags are m0+rh+ti*16+ln
  const int* gbase = gt + (size_t)k0 * M + m0 + rh + ln;

  bf8 rb0, rb1;            // B stage regs
  bf8 ra[4], rn[4];        // A frags: current / next stage
  int ga[4], gn[4];        // gather indices: current / next tap

  auto loadB = [&](int s) {
    const int kk = s / NCB, cb = s - kk * NCB;
    const unsigned short* pb =
        wt + ((size_t)(k0 + kk) * CO + row2) * CIN + cb * 32 + c0 * 8;
    rb0 = *(const bf8*)(pb);
    rb1 = *(const bf8*)(pb + 8);
  };
  auto writeB = [&](int buf) {
    *(bf8*)(sB[buf] + wsl0) = rb0;
    *(bf8*)(sB[buf] + wsl1) = rb1;
  };

  f4 acc[16];
  f4 zero = {0.f, 0.f, 0.f, 0.f};
#pragma unroll
  for (int i = 0; i < 16; ++i) acc[i] = zero;

  // prologue: tap-0 indices, stage-0 A/B
#pragma unroll
  for (int ti = 0; ti < 4; ++ti) ga[ti] = gbase[ti * 16];
  loadB(0);
#pragma unroll
  for (int ti = 0; ti < 4; ++ti)
    ra[ti] = *(const bf8*)(src + (size_t)ga[ti] * CIN + quad * 8);
  writeB(0);

  for (int s = 0; s < nstage; ++s) {
    const int buf = s & 1;
    const int kk = s / NCB, cb = s - kk * NCB;
    const bool have = (s + 1 < nstage);
    // prefetch indices one tap ahead
    if (cb == 0 && kk + 1 < nk) {
#pragma unroll
      for (int ti = 0; ti < 4; ++ti) gn[ti] = gbase[(size_t)(kk + 1) * M + ti * 16];
    }
    // prefetch next stage A/B into regs (overlaps this stage's MFMAs)
    if (have) {
      loadB(s + 1);
      const int cb1 = (cb + 1 < NCB) ? cb + 1 : 0;
      const int* gu = (cb + 1 < NCB) ? ga : gn;
#pragma unroll
      for (int ti = 0; ti < 4; ++ti)
        rn[ti] = *(const bf8*)(src + (size_t)gu[ti] * CIN + cb1 * 32 + quad * 8);
    }
    __syncthreads();                   // stage-s B writes visible
    const unsigned short* pb = sB[buf];
    bf8 bv[4];
#pragma unroll
    for (int tj = 0; tj < 4; ++tj)
      bv[tj] = *(const bf8*)(pb + (ch + tj * 16 + ln) * 32 + slot);
#pragma unroll
    for (int ti = 0; ti < 4; ++ti)
#pragma unroll
      for (int tj = 0; tj < 4; ++tj)
        acc[ti * 4 + tj] = __builtin_amdgcn_mfma_f32_16x16x32_bf16(
            ra[ti], bv[tj], acc[ti * 4 + tj], 0, 0, 0);
    if (have) {
      writeB(buf ^ 1);                 // vmcnt wait lands here, post-MFMA
#pragma unroll
      for (int ti = 0; ti < 4; ++ti) ra[ti] = rn[ti];
      if (cb + 1 == NCB) {
#pragma unroll
        for (int ti = 0; ti < 4; ++ti) ga[ti] = gn[ti];
      }
    }
  }

  // store bf16 partials: D layout col=ln, row=quad*4+rr
  unsigned short* pp = part + ((size_t)kpart * M + m0) * CO;
#pragma unroll
  for (int ti = 0; ti < 4; ++ti) {
    int mrow = rh + ti * 16 + quad * 4;
#pragma unroll
    for (int tj = 0; tj < 4; ++tj) {
      int co = ch + tj * 16 + ln;
#pragma unroll
      for (int rr = 0; rr < 4; ++rr)
        pp[(size_t)(mrow + rr) * CO + co] = f2bf(acc[ti * 4 + tj][rr]);
    }
  }
}

// ---------------- reduce 1: sum KP bf16 partials + bias + LN + silu -> h1 ----
__global__ __launch_bounds__(256) void k_r1(const unsigned short* __restrict__ p,
                                            const float* __restrict__ bias,
                                            unsigned short* __restrict__ h1) {
  int wave = threadIdx.x >> 6, lane = threadIdx.x & 63;
  int m = blockIdx.x * 4 + wave;
  float v0 = bias[lane], v1 = bias[lane + 64];
#pragma unroll
  for (int q = 0; q < KP; ++q) {
    const unsigned short* pq = p + ((size_t)q * M + m) * CO;
    v0 += bf2f(pq[lane]);
    v1 += bf2f(pq[lane + 64]);
  }
  float sum = v0 + v1, sq = v0 * v0 + v1 * v1;
#pragma unroll
  for (int mk = 1; mk < 64; mk <<= 1) {
    sum += __shfl_xor(sum, mk, 64);
    sq  += __shfl_xor(sq, mk, 64);
  }
  float mean = sum / (float)CO;
  float var  = sq / (float)CO - mean * mean;
  float rstd = rsqrtf(var + EPS);
  float y0 = (v0 - mean) * rstd;
  float y1 = (v1 - mean) * rstd;
  float s0 = y0 / (1.f + __expf(-y0));
  float s1 = y1 / (1.f + __expf(-y1));
  h1[(size_t)m * CO + lane]      = f2bf(s0);
  h1[(size_t)m * CO + lane + 64] = f2bf(s1);
}

// ---------------- reduce 2: sum KP bf16 partials + bias + skip, *mask -> out -
__global__ __launch_bounds__(256) void k_r2(const unsigned short* __restrict__ p,
                                            const float* __restrict__ bias,
                                            const float* __restrict__ sres,
                                            const float* __restrict__ maskf,
                                            float* __restrict__ out) {
  int i = blockIdx.x * 256 + threadIdx.x;   // i in [0, M*CO/4)
  int m = i >> 5;                            // 32 groups of 4 per row
  int o4 = (i & 31) * 4;
  float4 acc = *(const float4*)(bias + o4);
#pragma unroll
  for (int q = 0; q < KP; ++q) {
    ushort4 a = *(const ushort4*)(p + ((size_t)q * M + m) * CO + o4);
    acc.x += bf2f(a.x); acc.y += bf2f(a.y);
    acc.z += bf2f(a.z); acc.w += bf2f(a.w);
  }
  float4 s = *(const float4*)(sres + (size_t)(m >> 3) * CO + o4);
  float mk = maskf[m];
  float4 r;
  r.x = (acc.x + s.x) * mk;
  r.y = (acc.y + s.y) * mk;
  r.z = (acc.z + s.z) * mk;
  r.w = (acc.w + s.w) * mk;
  *(float4*)(out + (size_t)m * CO + o4) = r;
}

// ---------------- launcher ----------------------------------------------------
extern "C" void kernel_launch(void* const* d_in, const int* in_sizes, int n_in,
                              void* d_out, int out_size, void* d_ws, size_t ws_size,
                              hipStream_t stream) {
  const float* feats = (const float*)d_in[0];
  const float* n1w   = (const float*)d_in[1];
  const float* n1b   = (const float*)d_in[2];
  const float* sdw   = (const float*)d_in[3];
  const float* sdb   = (const float*)d_in[4];
  const float* c1w   = (const float*)d_in[5];
  const float* c1b   = (const float*)d_in[6];
  const float* c2w   = (const float*)d_in[7];
  const float* c2b   = (const float*)d_in[8];
  const float* skw   = (const float*)d_in[9];
  const float* skb   = (const float*)d_in[10];
  const int* coords  = (const int*)d_in[11];
  float* out = (float*)d_out;   // [M*CO] conv output, then [N*8] subdiv

  char* ws = (char*)d_ws;
  size_t off = 0;
  auto alloc = [&](size_t bytes) -> char* {
    char* p = ws + off;
    off += (bytes + 255) & ~(size_t)255;
    return p;
  };
  unsigned short* h    = (unsigned short*)alloc((size_t)(N + 1) * C * 2);
  unsigned short* h1   = (unsigned short*)alloc((size_t)(M + 1) * CO * 2);
  int*   grid  = (int*)alloc((size_t)G * G * G * 4);
  int*   nidxt = (int*)alloc((size_t)27 * M * 4);
  int*   g1t   = (int*)alloc((size_t)27 * M * 4);
  int*   pidx  = (int*)alloc((size_t)M * 4);
  float* maskf = (float*)alloc((size_t)M * 4);
  float* sres  = (float*)alloc((size_t)N * CO * 4);
  unsigned short* w1t = (unsigned short*)alloc((size_t)27 * CO * C * 2);
  unsigned short* w2t = (unsigned short*)alloc((size_t)27 * CO * CO * 2);
  unsigned short* pc  = (unsigned short*)alloc((size_t)KP * M * CO * 2);

  k_prep<<<1296, 256, 0, stream>>>(c1w, w1t, c2w, w2t, grid, h, h1);
  k_rownorm<<<N, 256, 0, stream>>>(feats, n1w, n1b, sdw, sdb,
                                   out + (size_t)M * CO, h, pidx, maskf,
                                   coords, grid, skw, skb, sres);
  k_nidx<<<(M * 27 + 255) / 256, 256, 0, stream>>>(coords, grid, pidx, nidxt, g1t);

  // conv1: CIN=256 (8 chunks of 32), k-split 6x4+3 -> 896 blocks
  k_conv<C, 8><<<dim3(M / 128, KP), 256, 0, stream>>>(h, g1t, w1t, pc);
  k_r1<<<M / 4, 256, 0, stream>>>(pc, c1b, h1);

  // conv2: CIN=128 (4 chunks of 32)
  k_conv<CO, 4><<<dim3(M / 128, KP), 256, 0, stream>>>(h1, nidxt, w2t, pc);
  k_r2<<<M * CO / 4 / 256, 256, 0, stream>>>(pc, c2b, sres, maskf, out);
}

// Round 9
// 193.756 us; speedup vs baseline: 1.3455x; 1.0465x over previous
//
#include <hip/hip_runtime.h>
#include <cstdint>
#include <cstddef>

// Problem constants (from reference)
constexpr int N  = 2048;     // parents
constexpr int C  = 256;      // in channels
constexpr int CO = 128;      // out channels
constexpr int M  = 16384;    // children (8*N)
constexpr int G  = 66;       // padded child grid dim (S2+2)
constexpr int KP = 6;        // k-split parts
constexpr int KCHUNK = 5;    // neighbors per part (5,5,5,5,5,2)
constexpr float EPS = 1e-6f;

using bf8 = __attribute__((ext_vector_type(8))) short;   // 8 bf16 (4 VGPRs)
using f4  = __attribute__((ext_vector_type(4))) float;   // 4 f32 acc

static __device__ __forceinline__ unsigned short f2bf(float f) {
  unsigned u = __float_as_uint(f);
  u += 0x7fffu + ((u >> 16) & 1u);     // round-to-nearest-even
  return (unsigned short)(u >> 16);
}
static __device__ __forceinline__ float bf2f(unsigned short s) {
  return __uint_as_float((unsigned)s << 16);
}

// ------ prep: tiled weight transposes (coalesced both sides) + grid init -----
__global__ __launch_bounds__(256) void k_prep(
    const float* __restrict__ c1w, unsigned short* __restrict__ w1t,
    const float* __restrict__ c2w, unsigned short* __restrict__ w2t,
    int* __restrict__ grid, unsigned short* __restrict__ h,
    unsigned short* __restrict__ h1) {
  int i = blockIdx.x * 256 + threadIdx.x;
  if (i < G * G * G) grid[i] = M;
  if (blockIdx.x == 1200) {
    if (threadIdx.x < C) h[(size_t)N * C + threadIdx.x] = 0;
  }
  if (blockIdx.x == 1201) {
    if (threadIdx.x < CO) h1[(size_t)M * CO + threadIdx.x] = 0;
  }

  __shared__ float tile[32][33];
  int bx = blockIdx.x;
  const float* w; unsigned short* wtp; int cin, k, cb, ob;
  if (bx < 864) {                      // conv1: CIN=256 -> 8 cb x 4 ob per k
    w = c1w; wtp = w1t; cin = C;
    k = bx >> 5; int tl = bx & 31; cb = tl >> 2; ob = tl & 3;
  } else {                             // conv2: CIN=128 -> 4 cb x 4 ob per k
    int b2 = bx - 864;
    w = c2w; wtp = w2t; cin = CO;
    k = b2 >> 4; int tl = b2 & 15; cb = tl >> 2; ob = tl & 3;
  }
  int ty = threadIdx.x >> 5, tx = threadIdx.x & 31;
#pragma unroll
  for (int j = 0; j < 4; ++j) {        // read w[k][cb*32+row][ob*32+tx]
    int row = ty + j * 8;
    tile[row][tx] = w[((size_t)k * cin + cb * 32 + row) * CO + ob * 32 + tx];
  }
  __syncthreads();
#pragma unroll
  for (int j = 0; j < 4; ++j) {        // write wt[k][ob*32+row][cb*32+tx]
    int row = ty + j * 8;
    wtp[((size_t)k * CO + ob * 32 + row) * cin + cb * 32 + tx] =
        f2bf(tile[tx][row]);
  }
}

// --- per-parent: subdiv + mask + LN + silu -> h; child scatter; skip GEMM ----
__global__ __launch_bounds__(256) void k_rownorm(
    const float* __restrict__ feats, const float* __restrict__ n1w,
    const float* __restrict__ n1b, const float* __restrict__ sdw,
    const float* __restrict__ sdb, float* __restrict__ out_subdiv,
    unsigned short* __restrict__ h, int* __restrict__ pidx,
    float* __restrict__ maskf, const int* __restrict__ coords,
    int* __restrict__ grid, const float* __restrict__ skw,
    const float* __restrict__ skb, float* __restrict__ sres) {
  int n = blockIdx.x, t = threadIdx.x;
  __shared__ float sx[256];
  __shared__ float sacc[256];
  float x = feats[(size_t)n * C + t];
  sx[t] = x;
  float4 w0 = *(const float4*)(sdw + t * 8);
  float4 w1 = *(const float4*)(sdw + t * 8 + 4);
  float v[10] = {x * w0.x, x * w0.y, x * w0.z, x * w0.w,
                 x * w1.x, x * w1.y, x * w1.z, x * w1.w, x, x * x};
#pragma unroll
  for (int mk = 1; mk < 64; mk <<= 1) {
#pragma unroll
    for (int j = 0; j < 10; ++j) v[j] += __shfl_xor(v[j], mk, 64);
  }
  __shared__ float red[4][10];
  int wave = t >> 6, lane = t & 63;
  if (lane == 0) {
#pragma unroll
    for (int j = 0; j < 10; ++j) red[wave][j] = v[j];
  }
  __syncthreads();
  float sums[10];
#pragma unroll
  for (int j = 0; j < 10; ++j)
    sums[j] = red[0][j] + red[1][j] + red[2][j] + red[3][j];
  float mean = sums[8] / (float)C;
  float var  = sums[9] / (float)C - mean * mean;
  float rstd = rsqrtf(var + EPS);
  if (t < 8) {
    float sd = sums[t] + sdb[t];
    out_subdiv[(size_t)n * 8 + t] = sd;
    bool mk = sd > 0.f;
    pidx[n * 8 + t]  = mk ? n : N;   // h row index (N = zero row)
    maskf[n * 8 + t] = mk ? 1.f : 0.f;
    int xx = coords[n * 3 + 0] * 2 + ((t >> 2) & 1) + 1;
    int yy = coords[n * 3 + 1] * 2 + ((t >> 1) & 1) + 1;
    int zz = coords[n * 3 + 2] * 2 + (t & 1) + 1;
    grid[(xx * G + yy) * G + zz] = n * 8 + t;
  }
  float y  = (x - mean) * rstd * n1w[t] + n1b[t];
  float sl = y / (1.f + __expf(-y));
  h[(size_t)n * C + t] = f2bf(sl);

  // skip GEMM: thread (o = t&127, half = t>>7) sums 128 channels
  int o = t & 127, half = t >> 7;
  const float* wp = skw + (size_t)(half * 128) * CO + o;
  const float* xs = sx + half * 128;
  float a = 0.f;
#pragma unroll 8
  for (int c = 0; c < 128; ++c) a += xs[c] * wp[(size_t)c * CO];
  sacc[t] = a;
  __syncthreads();
  if (t < 128) sres[(size_t)n * CO + t] = sacc[t] + sacc[t + 128] + skb[t];
}

// ---------------- implicit-GEMM conv: A direct from L2, B through LDS --------
// Block: 128 rows x 128 cols, taps [k0,k0+nk) (KP-way split). grid=(M/128,KP)
// = 768 = exactly 3 blocks/CU (grid MUST be a multiple of 256*blocks/CU:
// r8's 896 = 3.5/CU left a half-empty tail round, occupancy 19%).
// Gather indices computed INLINE from coords/grid/pidx (no precomputed
// tables): per lane 4 grid-base offsets in prologue; per tap one uniform
// doff + 4 grid loads (+4 pidx loads when UP). Prefetched one tap ahead.
// A fragments: per-lane 16B gathers straight from L2. B staged reg->LDS
// double-buffered (8KB/buf, XOR swizzle).
// __launch_bounds__(256,3): 170 reg cap >= ~140 needed -> no spill.
// (256,4) spills to scratch (r7: WRITE +15MB, MfmaUtil halved) - do not re-try.
template <int CIN, int NCB, bool UP>
__global__ __launch_bounds__(256, 3) void k_conv(
    const unsigned short* __restrict__ src, const int* __restrict__ coords,
    const int* __restrict__ grid, const int* __restrict__ pidx,
    const unsigned short* __restrict__ wt, unsigned short* __restrict__ part) {
  __shared__ unsigned short sB[2][128 * 32];   // 8 KB per buf
  const int t = threadIdx.x;
  const int w = t >> 6, lane = t & 63;
  const int quad = lane >> 4, ln = lane & 15;
  const int m0 = blockIdx.x * 128;
  const int kpart = blockIdx.y;
  const int k0 = kpart * KCHUNK;
  const int nk = min(KCHUNK, 27 - k0);
  const int nstage = nk * NCB;
  const int rh = (w >> 1) * 64, ch = (w & 1) * 64;

  // B staging: thread covers wt row row2 = t>>1, chunks c0, c0+1 (XOR swizzle)
  const int row2 = t >> 1;
  const int c0 = (t & 1) * 2;
  const int x3 = (row2 >> 1) & 3;
  const int wsl0 = row2 * 32 + ((c0) ^ x3) * 8;
  const int wsl1 = row2 * 32 + ((c0 + 1) ^ x3) * 8;
  const int slot = (quad ^ ((ln >> 1) & 3)) * 8;   // de-swizzle for frag reads

  // per-lane grid base offsets for the 4 A-rows (child m = m0+rh+ti*16+ln)
  int gb[4];
#pragma unroll
  for (int ti = 0; ti < 4; ++ti) {
    int m = m0 + rh + ti * 16 + ln;
    int p = m >> 3, j = m & 7;
    int cx = coords[p * 3 + 0] * 2 + ((j >> 2) & 1) + 1;
    int cy = coords[p * 3 + 1] * 2 + ((j >> 1) & 1) + 1;
    int cz = coords[p * 3 + 2] * 2 + (j & 1) + 1;
    gb[ti] = (cx * G + cy) * G + cz;
  }
  auto tapoff = [&](int k) {           // wave-uniform neighbor offset
    return (k / 9 - 1) * (G * G) + ((k / 3) % 3 - 1) * G + (k % 3 - 1);
  };
  auto lookup = [&](int ti, int doff) {
    int g = grid[gb[ti] + doff];
    if (UP) return (g >= M) ? N : pidx[g & (M - 1)];
    return g;
  };

  bf8 rb0, rb1;            // B stage regs
  bf8 ra[4], rn[4];        // A frags: current / next stage
  int ga[4], gn[4];        // gather row indices: current / next tap

  auto loadB = [&](int s) {
    const int kk = s / NCB, cb = s - kk * NCB;
    const unsigned short* pb =
        wt + ((size_t)(k0 + kk) * CO + row2) * CIN + cb * 32 + c0 * 8;
    rb0 = *(const bf8*)(pb);
    rb1 = *(const bf8*)(pb + 8);
  };
  auto writeB = [&](int buf) {
    *(bf8*)(sB[buf] + wsl0) = rb0;
    *(bf8*)(sB[buf] + wsl1) = rb1;
  };

  f4 acc[16];
  f4 zero = {0.f, 0.f, 0.f, 0.f};
#pragma unroll
  for (int i = 0; i < 16; ++i) acc[i] = zero;

  // prologue: tap-0 indices, stage-0 A/B
  {
    int d0 = tapoff(k0);
#pragma unroll
    for (int ti = 0; ti < 4; ++ti) ga[ti] = lookup(ti, d0);
  }
  loadB(0);
#pragma unroll
  for (int ti = 0; ti < 4; ++ti)
    ra[ti] = *(const bf8*)(src + (size_t)ga[ti] * CIN + quad * 8);
  writeB(0);

  for (int s = 0; s < nstage; ++s) {
    const int buf = s & 1;
    const int kk = s / NCB, cb = s - kk * NCB;
    const bool have = (s + 1 < nstage);
    // prefetch indices one tap ahead
    if (cb == 0 && kk + 1 < nk) {
      int dn = tapoff(k0 + kk + 1);
#pragma unroll
      for (int ti = 0; ti < 4; ++ti) gn[ti] = lookup(ti, dn);
    }
    // prefetch next stage A/B into regs (overlaps this stage's MFMAs)
    if (have) {
      loadB(s + 1);
      const int cb1 = (cb + 1 < NCB) ? cb + 1 : 0;
      const int* gu = (cb + 1 < NCB) ? ga : gn;
#pragma unroll
      for (int ti = 0; ti < 4; ++ti)
        rn[ti] = *(const bf8*)(src + (size_t)gu[ti] * CIN + cb1 * 32 + quad * 8);
    }
    __syncthreads();                   // stage-s B writes visible
    const unsigned short* pb = sB[buf];
    bf8 bv[4];
#pragma unroll
    for (int tj = 0; tj < 4; ++tj)
      bv[tj] = *(const bf8*)(pb + (ch + tj * 16 + ln) * 32 + slot);
#pragma unroll
    for (int ti = 0; ti < 4; ++ti)
#pragma unroll
      for (int tj = 0; tj < 4; ++tj)
        acc[ti * 4 + tj] = __builtin_amdgcn_mfma_f32_16x16x32_bf16(
            ra[ti], bv[tj], acc[ti * 4 + tj], 0, 0, 0);
    if (have) {
      writeB(buf ^ 1);                 // vmcnt wait lands here, post-MFMA
#pragma unroll
      for (int ti = 0; ti < 4; ++ti) ra[ti] = rn[ti];
      if (cb + 1 == NCB) {
#pragma unroll
        for (int ti = 0; ti < 4; ++ti) ga[ti] = gn[ti];
      }
    }
  }

  // store bf16 partials: D layout col=ln, row=quad*4+rr
  unsigned short* pp = part + ((size_t)kpart * M + m0) * CO;
#pragma unroll
  for (int ti = 0; ti < 4; ++ti) {
    int mrow = rh + ti * 16 + quad * 4;
#pragma unroll
    for (int tj = 0; tj < 4; ++tj) {
      int co = ch + tj * 16 + ln;
#pragma unroll
      for (int rr = 0; rr < 4; ++rr)
        pp[(size_t)(mrow + rr) * CO + co] = f2bf(acc[ti * 4 + tj][rr]);
    }
  }
}

// ---------------- reduce 1: sum KP bf16 partials + bias + LN + silu -> h1 ----
__global__ __launch_bounds__(256) void k_r1(const unsigned short* __restrict__ p,
                                            const float* __restrict__ bias,
                                            unsigned short* __restrict__ h1) {
  int wave = threadIdx.x >> 6, lane = threadIdx.x & 63;
  int m = blockIdx.x * 4 + wave;
  float v0 = bias[lane], v1 = bias[lane + 64];
#pragma unroll
  for (int q = 0; q < KP; ++q) {
    const unsigned short* pq = p + ((size_t)q * M + m) * CO;
    v0 += bf2f(pq[lane]);
    v1 += bf2f(pq[lane + 64]);
  }
  float sum = v0 + v1, sq = v0 * v0 + v1 * v1;
#pragma unroll
  for (int mk = 1; mk < 64; mk <<= 1) {
    sum += __shfl_xor(sum, mk, 64);
    sq  += __shfl_xor(sq, mk, 64);
  }
  float mean = sum / (float)CO;
  float var  = sq / (float)CO - mean * mean;
  float rstd = rsqrtf(var + EPS);
  float y0 = (v0 - mean) * rstd;
  float y1 = (v1 - mean) * rstd;
  float s0 = y0 / (1.f + __expf(-y0));
  float s1 = y1 / (1.f + __expf(-y1));
  h1[(size_t)m * CO + lane]      = f2bf(s0);
  h1[(size_t)m * CO + lane + 64] = f2bf(s1);
}

// ---------------- reduce 2: sum KP bf16 partials + bias + skip, *mask -> out -
__global__ __launch_bounds__(256) void k_r2(const unsigned short* __restrict__ p,
                                            const float* __restrict__ bias,
                                            const float* __restrict__ sres,
                                            const float* __restrict__ maskf,
                                            float* __restrict__ out) {
  int i = blockIdx.x * 256 + threadIdx.x;   // i in [0, M*CO/4)
  int m = i >> 5;                            // 32 groups of 4 per row
  int o4 = (i & 31) * 4;
  float4 acc = *(const float4*)(bias + o4);
#pragma unroll
  for (int q = 0; q < KP; ++q) {
    ushort4 a = *(const ushort4*)(p + ((size_t)q * M + m) * CO + o4);
    acc.x += bf2f(a.x); acc.y += bf2f(a.y);
    acc.z += bf2f(a.z); acc.w += bf2f(a.w);
  }
  float4 s = *(const float4*)(sres + (size_t)(m >> 3) * CO + o4);
  float mk = maskf[m];
  float4 r;
  r.x = (acc.x + s.x) * mk;
  r.y = (acc.y + s.y) * mk;
  r.z = (acc.z + s.z) * mk;
  r.w = (acc.w + s.w) * mk;
  *(float4*)(out + (size_t)m * CO + o4) = r;
}

// ---------------- launcher ----------------------------------------------------
extern "C" void kernel_launch(void* const* d_in, const int* in_sizes, int n_in,
                              void* d_out, int out_size, void* d_ws, size_t ws_size,
                              hipStream_t stream) {
  const float* feats = (const float*)d_in[0];
  const float* n1w   = (const float*)d_in[1];
  const float* n1b   = (const float*)d_in[2];
  const float* sdw   = (const float*)d_in[3];
  const float* sdb   = (const float*)d_in[4];
  const float* c1w   = (const float*)d_in[5];
  const float* c1b   = (const float*)d_in[6];
  const float* c2w   = (const float*)d_in[7];
  const float* c2b   = (const float*)d_in[8];
  const float* skw   = (const float*)d_in[9];
  const float* skb   = (const float*)d_in[10];
  const int* coords  = (const int*)d_in[11];
  float* out = (float*)d_out;   // [M*CO] conv output, then [N*8] subdiv

  char* ws = (char*)d_ws;
  size_t off = 0;
  auto alloc = [&](size_t bytes) -> char* {
    char* p = ws + off;
    off += (bytes + 255) & ~(size_t)255;
    return p;
  };
  unsigned short* h    = (unsigned short*)alloc((size_t)(N + 1) * C * 2);
  unsigned short* h1   = (unsigned short*)alloc((size_t)(M + 1) * CO * 2);
  int*   grid  = (int*)alloc((size_t)G * G * G * 4);
  int*   pidx  = (int*)alloc((size_t)M * 4);
  float* maskf = (float*)alloc((size_t)M * 4);
  float* sres  = (float*)alloc((size_t)N * CO * 4);
  unsigned short* w1t = (unsigned short*)alloc((size_t)27 * CO * C * 2);
  unsigned short* w2t = (unsigned short*)alloc((size_t)27 * CO * CO * 2);
  unsigned short* pc  = (unsigned short*)alloc((size_t)KP * M * CO * 2);

  k_prep<<<1296, 256, 0, stream>>>(c1w, w1t, c2w, w2t, grid, h, h1);
  k_rownorm<<<N, 256, 0, stream>>>(feats, n1w, n1b, sdw, sdb,
                                   out + (size_t)M * CO, h, pidx, maskf,
                                   coords, grid, skw, skb, sres);

  // conv1: CIN=256 (8 chunks of 32), k-split 5x5+2 -> 768 blocks (3/CU exact)
  k_conv<C, 8, true><<<dim3(M / 128, KP), 256, 0, stream>>>(h, coords, grid,
                                                            pidx, w1t, pc);
  k_r1<<<M / 4, 256, 0, stream>>>(pc, c1b, h1);

  // conv2: CIN=128 (4 chunks of 32)
  k_conv<CO, 4, false><<<dim3(M / 128, KP), 256, 0, stream>>>(h1, coords, grid,
                                                              pidx, w2t, pc);
  k_r2<<<M * CO / 4 / 256, 256, 0, stream>>>(pc, c2b, sres, maskf, out);
}